// Round 1
// baseline (205.861 us; speedup 1.0000x reference)
//
#include <hip/hip_runtime.h>
#include <math.h>

#define NB 32
#define HQ 16
#define DN 128
#define DR 64
#define DQT 192      // DN + DR
#define DV 128
#define PAGE 64
#define MAXP 64
#define NSPLIT 16
#define SPLIT_PAGES 4
#define SPLIT_T (SPLIT_PAGES * PAGE)   // 256 tokens per split
#define SM_SCALE 0.07216878364870322f

// Partial flash-decode: one block = (batch b, kv-split). Wave w handles page w
// of the split for scores (lane = token); PV phase remaps lane -> d.
__global__ __launch_bounds__(256, 2)
void attn_partial_kernel(const float* __restrict__ q,
                         const float* __restrict__ kn,
                         const float* __restrict__ kr,
                         const float* __restrict__ v,
                         const int* __restrict__ seq_lens,
                         const int* __restrict__ block_table,
                         float* __restrict__ o_part,   // [NB][NSPLIT][HQ][DV]
                         float* __restrict__ ml_part)  // [NB][NSPLIT][HQ][2]
{
    const int split = blockIdx.x;
    const int b = blockIdx.y;
    const int seq = seq_lens[b];
    const int t0 = split * SPLIT_T;
    if (t0 >= seq) return;

    const int tid = (int)threadIdx.x;
    const int wave = tid >> 6;
    const int lane = tid & 63;

    __shared__ float q_s[HQ * DQT];                 // 12 KB
    __shared__ float p_s[SPLIT_T][HQ];              // 16 KB, rows 64B aligned
    __shared__ float redmax_s[SPLIT_PAGES][HQ];
    __shared__ float redsum_s[SPLIT_PAGES][HQ];
    __shared__ float acc_s[DV][HQ + 1];             // +1 pad: kill bank conflicts
    __shared__ int bt_s[SPLIT_PAGES];

    // stage q (3072 floats = 768 float4, 3 per thread) and page ids
    {
        const float4* qb = (const float4*)(q + (size_t)b * HQ * DQT);
        float4* qs4 = (float4*)q_s;
        #pragma unroll
        for (int i = 0; i < 3; i++) qs4[tid + 256 * i] = qb[tid + 256 * i];
    }
    if (tid < SPLIT_PAGES)
        bt_s[tid] = block_table[b * MAXP + split * SPLIT_PAGES + tid];
    __syncthreads();

    // ---- phase 1: scores s[h] for this lane's token ----
    float s[HQ];
    #pragma unroll
    for (int h = 0; h < HQ; h++) s[h] = 0.f;

    const int pbase = t0 + wave * PAGE;
    const bool wave_valid = pbase < seq;        // wave-uniform
    const bool valid = (pbase + lane) < seq;

    if (wave_valid) {
        const int pid = bt_s[wave];
        const float4* knp = (const float4*)(kn + ((size_t)pid * PAGE + lane) * DN);
        #pragma unroll 8
        for (int c = 0; c < DN / 4; c++) {
            float4 k4 = knp[c];
            #pragma unroll
            for (int h = 0; h < HQ; h++) {
                float4 q4 = ((const float4*)(q_s + h * DQT))[c];   // LDS broadcast
                s[h] += q4.x * k4.x + q4.y * k4.y + q4.z * k4.z + q4.w * k4.w;
            }
        }
        const float4* krp = (const float4*)(kr + ((size_t)pid * PAGE + lane) * DR);
        #pragma unroll 8
        for (int c = 0; c < DR / 4; c++) {
            float4 k4 = krp[c];
            #pragma unroll
            for (int h = 0; h < HQ; h++) {
                float4 q4 = ((const float4*)(q_s + h * DQT))[DN / 4 + c];
                s[h] += q4.x * k4.x + q4.y * k4.y + q4.z * k4.z + q4.w * k4.w;
            }
        }
    }
    #pragma unroll
    for (int h = 0; h < HQ; h++) s[h] = valid ? s[h] * SM_SCALE : -INFINITY;

    // ---- phase 2: block-wide softmax max, p = exp(s - m), sums ----
    #pragma unroll
    for (int h = 0; h < HQ; h++) {
        float m = s[h];
        #pragma unroll
        for (int off = 32; off > 0; off >>= 1) m = fmaxf(m, __shfl_xor(m, off));
        if (lane == 0) redmax_s[wave][h] = m;
    }
    __syncthreads();

    #pragma unroll
    for (int h = 0; h < HQ; h++) {
        float m = fmaxf(fmaxf(redmax_s[0][h], redmax_s[1][h]),
                        fmaxf(redmax_s[2][h], redmax_s[3][h]));
        s[h] = __expf(s[h] - m);    // invalid lanes: exp(-inf) = 0
    }
    {   // store probs token-major for the PV phase (float4 rows)
        const int t = wave * PAGE + lane;
        float4* prow = (float4*)(&p_s[t][0]);
        #pragma unroll
        for (int j = 0; j < 4; j++) {
            float4 pv;
            pv.x = s[4 * j + 0]; pv.y = s[4 * j + 1];
            pv.z = s[4 * j + 2]; pv.w = s[4 * j + 3];
            prow[j] = pv;
        }
    }
    #pragma unroll
    for (int h = 0; h < HQ; h++) {
        float l = s[h];
        #pragma unroll
        for (int off = 32; off > 0; off >>= 1) l += __shfl_xor(l, off);
        if (lane == 0) redsum_s[wave][h] = l;
    }
    __syncthreads();

    if (tid < HQ) {
        const int h = tid;
        float m = fmaxf(fmaxf(redmax_s[0][h], redmax_s[1][h]),
                        fmaxf(redmax_s[2][h], redmax_s[3][h]));
        float l = redsum_s[0][h] + redsum_s[1][h] + redsum_s[2][h] + redsum_s[3][h];
        float* ml = ml_part + ((size_t)(b * NSPLIT + split) * HQ + h) * 2;
        ml[0] = m;
        ml[1] = l;
    }

    // ---- phase 3: PV. lane -> d (two token-parity groups), coalesced V ----
    const int g = tid >> 7;      // token parity group
    const int d = tid & 127;
    float acc[HQ];
    #pragma unroll
    for (int h = 0; h < HQ; h++) acc[h] = 0.f;

    #pragma unroll
    for (int w = 0; w < SPLIT_PAGES; w++) {
        const int base = w * PAGE;
        if (t0 + base >= seq) break;
        const int pid = bt_s[w];
        int rem = seq - t0 - base;
        const int lim = rem < PAGE ? rem : PAGE;
        const float* vp = v + (size_t)pid * PAGE * DV + d;
        #pragma unroll 4
        for (int l2 = g; l2 < lim; l2 += 2) {
            float vv = vp[(size_t)l2 * DV];
            const float4* prow = (const float4*)(&p_s[base + l2][0]);
            #pragma unroll
            for (int j = 0; j < 4; j++) {
                float4 p4 = prow[j];   // LDS broadcast
                acc[4 * j + 0] += p4.x * vv;
                acc[4 * j + 1] += p4.y * vv;
                acc[4 * j + 2] += p4.z * vv;
                acc[4 * j + 3] += p4.w * vv;
            }
        }
    }

    if (g == 1) {
        #pragma unroll
        for (int h = 0; h < HQ; h++) acc_s[d][h] = acc[h];
    }
    __syncthreads();
    if (g == 0) {
        float* op = o_part + ((size_t)(b * NSPLIT + split) * HQ) * DV + d;
        #pragma unroll
        for (int h = 0; h < HQ; h++)
            op[h * DV] = acc[h] + acc_s[d][h];
    }
}

// Merge partials across splits (log-sum-exp combine).
__global__ __launch_bounds__(128)
void attn_combine_kernel(const float* __restrict__ o_part,
                         const float* __restrict__ ml_part,
                         const int* __restrict__ seq_lens,
                         float* __restrict__ out)
{
    const int h = blockIdx.x;
    const int b = blockIdx.y;
    const int d = (int)threadIdx.x;
    const int seq = seq_lens[b];
    int ns = (seq + SPLIT_T - 1) / SPLIT_T;
    if (ns > NSPLIT) ns = NSPLIT;

    float M = -INFINITY, den = 0.f, acc = 0.f;
    for (int s2 = 0; s2 < ns; s2++) {
        const float* ml = ml_part + ((size_t)(b * NSPLIT + s2) * HQ + h) * 2;
        float m = ml[0], l = ml[1];
        float o = o_part[((size_t)(b * NSPLIT + s2) * HQ + h) * DV + d];
        float nM = fmaxf(M, m);
        float eo = __expf(M - nM);   // first iter: exp(-inf) = 0
        float en = __expf(m - nM);
        acc = acc * eo + o * en;
        den = den * eo + l * en;
        M = nM;
    }
    out[((size_t)b * HQ + h) * DV + d] = acc / den;
}

extern "C" void kernel_launch(void* const* d_in, const int* in_sizes, int n_in,
                              void* d_out, int out_size, void* d_ws, size_t ws_size,
                              hipStream_t stream)
{
    const float* q  = (const float*)d_in[0];
    const float* kn = (const float*)d_in[1];
    const float* kr = (const float*)d_in[2];
    const float* v  = (const float*)d_in[3];
    const int* seq_lens    = (const int*)d_in[4];
    const int* block_table = (const int*)d_in[5];

    float* o_part  = (float*)d_ws;                                  // 4 MB
    float* ml_part = o_part + (size_t)NB * NSPLIT * HQ * DV;        // 64 KB

    attn_partial_kernel<<<dim3(NSPLIT, NB), 256, 0, stream>>>(
        q, kn, kr, v, seq_lens, block_table, o_part, ml_part);
    attn_combine_kernel<<<dim3(HQ, NB), 128, 0, stream>>>(
        o_part, ml_part, seq_lens, (float*)d_out);
}